// Round 5
// baseline (1070.111 us; speedup 1.0000x reference)
//
#include <hip/hip_runtime.h>

#define NROWS 32768
#define DDIM  512
#define KCENT 8192
#define BM 64               // rows per block
#define NCT 64              // centroid tiles of 128 cols
#define NSTEP (NCT*16)      // BK=32 chunks: 16 per tile, 1024 total

// out layout (floats): qout[16777216] loss[16777216] idx[32768] cbv[4194304] counts[8192]
#define O_LOSS 16777216
#define O_IDX  33554432
#define O_CBV  33587200
#define O_CNT  37781504

#define XT_BYTES 65536      // 64 rows * 1024 B (512 f16)
#define BB_BYTES 8192       // B chunk: 128 rows * 64 B (32 f16)

typedef float f32x4 __attribute__((ext_vector_type(4)));
typedef _Float16 f16x8 __attribute__((ext_vector_type(8)));

// ---- kernel 0a: fp32 -> f16, plain row-major (for X) ----
__global__ __launch_bounds__(256) void vq_cvt_plain(
    const float* __restrict__ src, char* __restrict__ dst)
{
    const size_t gid = (size_t)blockIdx.x * 256 + threadIdx.x;  // one 16B unit
    const float4* p = (const float4*)(src + gid * 8);
    float4 a = p[0], b = p[1];
    f16x8 h;
    h[0]=(_Float16)a.x; h[1]=(_Float16)a.y; h[2]=(_Float16)a.z; h[3]=(_Float16)a.w;
    h[4]=(_Float16)b.x; h[5]=(_Float16)b.y; h[6]=(_Float16)b.z; h[7]=(_Float16)b.w;
    *(f16x8*)(dst + gid * 16) = h;
}

// ---- kernel 0b: CB fp32 -> f16 into chunked+permuted layout ----
// layout: [step s = ct*16+dks][r 0..127][w 0..3], 16B units;
// flat unit (s, r, w) holds logical k-unit (w ^ ((r>>1)&3)) of row ct*128+r,
// dims dks*32 + k_unit*8 .. +8
__global__ __launch_bounds__(256) void vq_cvt_cb(
    const float* __restrict__ src, char* __restrict__ dst)
{
    const int gid  = blockIdx.x * 256 + threadIdx.x;
    const int s    = gid >> 9;          // 1024 chunks
    const int rw   = gid & 511;
    const int r    = rw >> 2, w = rw & 3;
    const int ct   = s >> 4, dks = s & 15;
    const int ku   = w ^ ((r >> 1) & 3);
    const float4* p = (const float4*)(src + (size_t)(ct*128 + r) * DDIM + dks*32 + ku*8);
    float4 a = p[0], b = p[1];
    f16x8 h;
    h[0]=(_Float16)a.x; h[1]=(_Float16)a.y; h[2]=(_Float16)a.z; h[3]=(_Float16)a.w;
    h[4]=(_Float16)b.x; h[5]=(_Float16)b.y; h[6]=(_Float16)b.z; h[7]=(_Float16)b.w;
    *(f16x8*)(dst + (size_t)gid * 16) = h;
}

// ---- kernel 1: centroid squared norms (fp64 accumulate) + counts=1 ----
__global__ __launch_bounds__(256) void vq_cnorm_kernel(
    const float* __restrict__ CB, float* __restrict__ cnorm, float* __restrict__ counts)
{
    const int wid  = threadIdx.x >> 6;
    const int lane = threadIdx.x & 63;
    const int cid  = blockIdx.x * 4 + wid;
    const float4* p = (const float4*)(CB + (size_t)cid * DDIM + lane * 8);
    float4 a = p[0], b = p[1];
    double s = (double)a.x*a.x + (double)a.y*a.y + (double)a.z*a.z + (double)a.w*a.w
             + (double)b.x*b.x + (double)b.y*b.y + (double)b.z*b.z + (double)b.w*b.w;
    #pragma unroll
    for (int off = 32; off > 0; off >>= 1) s += __shfl_down(s, off);
    if (lane == 0) { cnorm[cid] = (float)s; counts[cid] = 1.0f; }
}

__device__ __forceinline__ void t2_update(float s, int c,
                                          float& v1, int& i1, float& v2, int& i2)
{
    if (s < v1)      { v2 = v1; i2 = i1; v1 = s; i1 = c; }
    else if (s < v2) { v2 = s;  i2 = c; }
}

__device__ __forceinline__ void t2_merge(float b1, int bi1, float b2, int bi2,
                                         float& a1, int& ai1, float& a2, int& ai2)
{
    if (b1 < a1 || (b1 == a1 && bi1 < ai1)) {
        float o1 = a1; int oi1 = ai1;
        a1 = b1; ai1 = bi1;
        if (b2 < o1 || (b2 == o1 && bi2 < oi1)) { a2 = b2; ai2 = bi2; }
        else                                    { a2 = o1; ai2 = oi1; }
    } else {
        if (b1 < a2 || (b1 == a2 && bi1 < ai2)) { a2 = b1; ai2 = bi1; }
    }
}

__device__ __forceinline__ void gl16(const char* g, const char* l)
{
    __builtin_amdgcn_global_load_lds(
        (const __attribute__((address_space(1))) void*)g,
        (__attribute__((address_space(3))) void*)l, 16, 0, 0);
}

// ---- kernel 2: f16 distance GEMM, X-tile LDS-resident, B dbuf, top-2 ----
// 256 threads, 4 waves (2 row-groups x 2 col-groups), 2 blocks/CU (80 KB LDS)
__global__ __launch_bounds__(256, 2) void vq_gemm_kernel(
    const char* __restrict__ Xf, const char* __restrict__ Cf,
    const float* __restrict__ cnorm, int* __restrict__ pmini2)
{
    __shared__ __align__(16) char lds[XT_BYTES + 2*BB_BYTES];   // 80 KB

    // bijective XCD swizzle (512 = 8 * 64)
    const int swz  = (blockIdx.x & 7) * 64 + (blockIdx.x >> 3);
    const int rb   = swz * BM;
    const int t    = threadIdx.x;
    const int lane = t & 63;
    const int wid  = t >> 6;
    const int wr   = wid & 1;    // 2 row-groups of 32
    const int wc   = wid >> 1;   // 2 col-groups of 64
    const int l15  = lane & 15;
    const int lg   = lane >> 4;

    // ---- stage X tile (64 KB) via registers, 8-slot XOR swizzle ----
    #pragma unroll
    for (int i = 0; i < 16; ++i) {
        const int g = i*256 + t, r = g >> 6, w = g & 63;
        uint4 d = *(const uint4*)(Xf + (size_t)rb*1024 + (size_t)g*16);
        *(uint4*)(&lds[r*1024 + ((w ^ (r & 7)) * 16)]) = d;
    }
    // stage B chunk 0 (linear: global layout is pre-permuted)
    gl16(Cf + (size_t)t*16,          &lds[XT_BYTES + wid*1024]);
    gl16(Cf + 4096 + (size_t)t*16,   &lds[XT_BYTES + 4096 + wid*1024]);
    __syncthreads();

    f32x4 acc[2][4];
    float rv1[2][4], rv2[2][4];
    int   ri1[2][4], ri2[2][4];
    #pragma unroll
    for (int m = 0; m < 2; ++m)
        #pragma unroll
        for (int n = 0; n < 4; ++n) {
            f32x4 z = {0.f,0.f,0.f,0.f};
            acc[m][n] = z;
            rv1[m][n] = 3.4e38f; rv2[m][n] = 3.4e38f;
            ri1[m][n] = 0x7fffffff; ri2[m][n] = 0x7fffffff;
        }

    int buf = 0;
    for (int ct = 0; ct < NCT; ++ct) {
        for (int dks = 0; dks < 16; ++dks) {
            const int s = ct*16 + dks;
            if (s + 1 < NSTEP) {
                const char* nb = Cf + (size_t)(s+1)*BB_BYTES;
                char* dd = &lds[XT_BYTES + (buf^1)*BB_BYTES + wid*1024];
                gl16(nb + (size_t)t*16,        dd);
                gl16(nb + 4096 + (size_t)t*16, dd + 4096);
            }
            f16x8 A[2], B[4];
            #pragma unroll
            for (int m = 0; m < 2; ++m) {
                const int r = wr*32 + m*16 + l15;
                A[m] = *(const f16x8*)(&lds[r*1024 + (((dks*4 + lg) ^ (r & 7)) * 16)]);
            }
            #pragma unroll
            for (int n = 0; n < 4; ++n) {
                const int r = wc*64 + n*16 + l15;
                B[n] = *(const f16x8*)(&lds[XT_BYTES + buf*BB_BYTES + r*64
                                            + ((lg ^ ((r >> 1) & 3)) * 16)]);
            }
            #pragma unroll
            for (int m = 0; m < 2; ++m)
                #pragma unroll
                for (int n = 0; n < 4; ++n)
                    acc[m][n] = __builtin_amdgcn_mfma_f32_16x16x32_f16(A[m], B[n], acc[m][n], 0, 0, 0);
            __syncthreads();
            buf ^= 1;
        }

        // per-tile epilogue: score = ||c||^2 - 2*dot ; running top-2 per row-slot
        #pragma unroll
        for (int n = 0; n < 4; ++n) {
            const int col = ct*128 + wc*64 + n*16 + l15;
            const float cn = cnorm[col];
            #pragma unroll
            for (int m = 0; m < 2; ++m) {
                #pragma unroll
                for (int j = 0; j < 4; ++j) {
                    const float sv = fmaf(-2.0f, acc[m][n][j], cn);
                    t2_update(sv, col, rv1[m][j], ri1[m][j], rv2[m][j], ri2[m][j]);
                }
                f32x4 z = {0.f,0.f,0.f,0.f};
                acc[m][n] = z;
            }
        }
    }

    // cross-lane top-2 merge over the 16 l15 lanes (same row, different cols)
    #pragma unroll
    for (int m = 0; m < 2; ++m)
        #pragma unroll
        for (int j = 0; j < 4; ++j) {
            #pragma unroll
            for (int off = 1; off <= 8; off <<= 1) {
                float b1 = __shfl_xor(rv1[m][j], off);
                float b2 = __shfl_xor(rv2[m][j], off);
                int  bi1 = __shfl_xor(ri1[m][j], off);
                int  bi2 = __shfl_xor(ri2[m][j], off);
                t2_merge(b1, bi1, b2, bi2, rv1[m][j], ri1[m][j], rv2[m][j], ri2[m][j]);
            }
        }

    // cross-wave merge over the 2 col-groups via LDS
    float* redv = (float*)&lds[0];      // [64][2][2]
    int*   redi = (int*)&lds[2048];     // [64][2][2]
    if (l15 == 0) {
        #pragma unroll
        for (int m = 0; m < 2; ++m)
            #pragma unroll
            for (int j = 0; j < 4; ++j) {
                const int rl = wr*32 + m*16 + lg*4 + j;
                redv[(rl*2 + wc)*2 + 0] = rv1[m][j];
                redv[(rl*2 + wc)*2 + 1] = rv2[m][j];
                redi[(rl*2 + wc)*2 + 0] = ri1[m][j];
                redi[(rl*2 + wc)*2 + 1] = ri2[m][j];
            }
    }
    __syncthreads();
    if (t < BM) {
        float a1 = redv[(t*2 + 0)*2 + 0], a2 = redv[(t*2 + 0)*2 + 1];
        int  ai1 = redi[(t*2 + 0)*2 + 0], ai2 = redi[(t*2 + 0)*2 + 1];
        t2_merge(redv[(t*2 + 1)*2 + 0], redi[(t*2 + 1)*2 + 0],
                 redv[(t*2 + 1)*2 + 1], redi[(t*2 + 1)*2 + 1],
                 a1, ai1, a2, ai2);
        const int row = rb + t;
        pmini2[row*2 + 0] = ai1;
        pmini2[row*2 + 1] = ai2;
    }
}

// ---- kernel 3: exact fp64 resolve of the 2 candidates + write all outputs ----
__global__ __launch_bounds__(256) void vq_resolve_out(
    const float* __restrict__ X, const float* __restrict__ CB,
    const int* __restrict__ pmini2, float* __restrict__ out)
{
    const int wid  = threadIdx.x >> 6;
    const int lane = threadIdx.x & 63;
    const int row  = blockIdx.x * 4 + wid;
    const int i0 = pmini2[row*2 + 0], i1 = pmini2[row*2 + 1];

    const float4* xp = (const float4*)(X + (size_t)row * DDIM + lane * 8);
    float4 xa = xp[0], xb = xp[1];
    const float4* p0 = (const float4*)(CB + (size_t)i0 * DDIM + lane * 8);
    float4 c0a = p0[0], c0b = p0[1];
    const float4* p1 = (const float4*)(CB + (size_t)i1 * DDIM + lane * 8);
    float4 c1a = p1[0], c1b = p1[1];

    double d0 = 0.0, d1 = 0.0, e;
    e = (double)xa.x - c0a.x; d0 += e*e;  e = (double)xa.y - c0a.y; d0 += e*e;
    e = (double)xa.z - c0a.z; d0 += e*e;  e = (double)xa.w - c0a.w; d0 += e*e;
    e = (double)xb.x - c0b.x; d0 += e*e;  e = (double)xb.y - c0b.y; d0 += e*e;
    e = (double)xb.z - c0b.z; d0 += e*e;  e = (double)xb.w - c0b.w; d0 += e*e;
    e = (double)xa.x - c1a.x; d1 += e*e;  e = (double)xa.y - c1a.y; d1 += e*e;
    e = (double)xa.z - c1a.z; d1 += e*e;  e = (double)xa.w - c1a.w; d1 += e*e;
    e = (double)xb.x - c1b.x; d1 += e*e;  e = (double)xb.y - c1b.y; d1 += e*e;
    e = (double)xb.z - c1b.z; d1 += e*e;  e = (double)xb.w - c1b.w; d1 += e*e;
    #pragma unroll
    for (int off = 1; off < 64; off <<= 1) {
        d0 += __shfl_xor(d0, off);
        d1 += __shfl_xor(d1, off);
    }

    const bool w1 = (d1 < d0) || (d1 == d0 && i1 < i0);
    const int idx = w1 ? i1 : i0;
    float4 qa, qb;
    qa.x = w1 ? c1a.x : c0a.x;  qa.y = w1 ? c1a.y : c0a.y;
    qa.z = w1 ? c1a.z : c0a.z;  qa.w = w1 ? c1a.w : c0a.w;
    qb.x = w1 ? c1b.x : c0b.x;  qb.y = w1 ? c1b.y : c0b.y;
    qb.z = w1 ? c1b.z : c0b.z;  qb.w = w1 ? c1b.w : c0b.w;

    float4 qoa, loa, qob, lob;
    float d, s;
    d = qa.x - xa.x; qoa.x = xa.x + d; s = d*d; loa.x = s + 0.25f*s;
    d = qa.y - xa.y; qoa.y = xa.y + d; s = d*d; loa.y = s + 0.25f*s;
    d = qa.z - xa.z; qoa.z = xa.z + d; s = d*d; loa.z = s + 0.25f*s;
    d = qa.w - xa.w; qoa.w = xa.w + d; s = d*d; loa.w = s + 0.25f*s;
    d = qb.x - xb.x; qob.x = xb.x + d; s = d*d; lob.x = s + 0.25f*s;
    d = qb.y - xb.y; qob.y = xb.y + d; s = d*d; lob.y = s + 0.25f*s;
    d = qb.z - xb.z; qob.z = xb.z + d; s = d*d; lob.z = s + 0.25f*s;
    d = qb.w - xb.w; qob.w = xb.w + d; s = d*d; lob.w = s + 0.25f*s;

    ((float4*)out)[(size_t)row*128 + lane*2 + 0] = qoa;
    ((float4*)out)[(size_t)row*128 + lane*2 + 1] = qob;
    ((float4*)(out + O_LOSS))[(size_t)row*128 + lane*2 + 0] = loa;
    ((float4*)(out + O_LOSS))[(size_t)row*128 + lane*2 + 1] = lob;
    if (lane == 0) out[O_IDX + row] = (float)idx;
}

extern "C" void kernel_launch(void* const* d_in, const int* in_sizes, int n_in,
                              void* d_out, int out_size, void* d_ws, size_t ws_size,
                              hipStream_t stream)
{
    const float* X  = (const float*)d_in[0];
    const float* CB = (const float*)d_in[1];
    float* out = (float*)d_out;

    // big f16 scratch lives in out regions (fully rewritten afterwards)
    char* XsB  = (char*)out;              // 32 MB plain f16 X        (qout region)
    char* CBsB = (char*)(out + O_LOSS);   //  8 MB chunked f16 CB     (loss region)

    float* cnorm  = (float*)d_ws;             // 8192 floats
    int*   pmini2 = (int*)(cnorm + KCENT);    // 2*32768 ints

    vq_cvt_plain<<<(NROWS*64)/256, 256, 0, stream>>>(X, XsB);
    vq_cvt_cb<<<(KCENT*64)/256, 256, 0, stream>>>(CB, CBsB);
    vq_cnorm_kernel<<<KCENT/4, 256, 0, stream>>>(CB, cnorm, out + O_CNT);
    vq_gemm_kernel<<<NROWS/BM, 256, 0, stream>>>(XsB, CBsB, cnorm, pmini2);
    vq_resolve_out<<<NROWS/4, 256, 0, stream>>>(X, CB, pmini2, out);
    hipMemcpyAsync(out + O_CBV, CB, (size_t)KCENT * DDIM * sizeof(float),
                   hipMemcpyDeviceToDevice, stream);
}